// Round 3
// baseline (511.391 us; speedup 1.0000x reference)
//
#include <hip/hip_runtime.h>
#include <math.h>
#include <stdint.h>

#define B_    128
#define N_    1369
#define DINO_ 384
#define CLIP_ 512
#define H_    8
#define CHUNKS 8
#define CH     172   // ceil(1369/8); last chunk = 165
#define TROWS  12    // rows per LDS stage tile (12*384*4B = 18 KiB per buffer)
#define SEGS   18    // TROWS*384/256 segments of 64 lanes x 16B
#define SMP    52    // padded per-lane float stride in merge LDS

// ---------------------------------------------------------------------------
// helpers
// ---------------------------------------------------------------------------
__device__ __forceinline__ float wave_sum(float v) {
  v += __shfl_xor(v, 1);  v += __shfl_xor(v, 2);  v += __shfl_xor(v, 4);
  v += __shfl_xor(v, 8);  v += __shfl_xor(v, 16); v += __shfl_xor(v, 32);
  return v;
}

// async global->LDS copy, 16B per lane. LDS dest = base + lane*16 (HW rule).
__device__ __forceinline__ void gld16(const float* g, float* lds_base) {
  __builtin_amdgcn_global_load_lds(
      (const __attribute__((address_space(1))) void*)g,
      (__attribute__((address_space(3))) void*)lds_base, 16, 0, 0);
}

// ---------------------------------------------------------------------------
// kqq: fused Q-projection + qk precompute.  grid 128 x 256.
// Phase 1: qs[c] = bq[c] + clip[b,:]·Wq[:,c]  (each thread 2 columns)
// Phase 2: qk[b, h*384+j] = rs * sum_d Wk[j][h*64+d] * qs[h*64+d]
// ---------------------------------------------------------------------------
__global__ __launch_bounds__(256) void kqq(const float* __restrict__ clip,
                                           const float* __restrict__ Wq,
                                           const float* __restrict__ bq,
                                           const float* __restrict__ Wk,
                                           const float* __restrict__ temp,
                                           float* __restrict__ qkout) {
  const int b = blockIdx.x, tid = threadIdx.x;
  __shared__ float cl[CLIP_], qs[CLIP_];
  cl[tid] = clip[b * CLIP_ + tid];
  cl[tid + 256] = clip[b * CLIP_ + tid + 256];
  __syncthreads();
  #pragma unroll
  for (int half = 0; half < 2; ++half) {
    const int cc = tid + 256 * half;
    float acc = bq[cc];
    #pragma unroll 8
    for (int j = 0; j < CLIP_; ++j) acc += cl[j] * Wq[j * CLIP_ + cc];
    qs[cc] = acc;
  }
  __syncthreads();
  const float rs = 1.0f / (8.0f * temp[0]);       // scale = sqrt(64)*temperature
  #pragma unroll 1
  for (int r = 0; r < 12; ++r) {
    const int e = tid + 256 * r;
    const int h = e / DINO_;
    const int j = e - h * DINO_;
    const float* wrow = Wk + (size_t)j * CLIP_ + h * 64;
    const float* qrow = qs + h * 64;
    float a0 = 0.f, a1 = 0.f, a2 = 0.f, a3 = 0.f;
    #pragma unroll
    for (int d = 0; d < 64; d += 4) {
      const float4 wv = *(const float4*)(wrow + d);
      const float4 qv = *(const float4*)(qrow + d);
      a0 += wv.x * qv.x;  a1 += wv.y * qv.y;
      a2 += wv.z * qv.z;  a3 += wv.w * qv.w;
    }
    qkout[(size_t)b * 3072 + e] = ((a0 + a1) + (a2 + a3)) * rs;
  }
}

// ---------------------------------------------------------------------------
// kmain: fused logits + (no-max) softmax numerator + attn-weighted dino sum.
// grid 1024 x 256 (exactly 4 blocks/CU at launch_bounds(256,4), 16 waves/CU).
//
// g=4 lane layout: 32-lane group Gg = lane>>5 serves heads 4G..4G+3;
// m = lane&31 owns dims 4m + 128t + z (t=0..2, z=0..3) -> 3 ds_read_b128/row.
// Octet head hO = 2*bit4 + bit3.  Logit fold: xor16 pair-fold (4 shfl),
// xor8 fold (2 shfl), xor4/2/1 DPP reduce, exp once, 3-shfl broadcast.
// s[j] accumulates head (hO ^ j); FMA count stays optimal (96/lane/row).
// ---------------------------------------------------------------------------
__global__ __launch_bounds__(256, 4) void kmain(const float* __restrict__ dino,
                                                const float* __restrict__ qk,
                                                float* __restrict__ ps,
                                                float* __restrict__ pl) {
  __shared__ float lds[2 * TROWS * DINO_];   // 2 x 4608 floats = 36 KiB
  __shared__ float lm[2][H_];

  const int blk = blockIdx.x;
  const int b = blk >> 3;
  const int c = blk & 7;
  const int n0 = c * CH;
  const int n1 = min(N_, n0 + CH);
  const int tid = threadIdx.x, w = tid >> 6, lane = tid & 63;
  const int m = lane & 31;
  const int G = lane >> 5;
  const int b4 = (lane >> 4) & 1, b3 = (lane >> 3) & 1;
  const int hO = 2 * b4 + b3;

  // qr[j][k]: q for relative head j (absolute 4G+j), dim 4m + 128t + z
  float qr[4][12];
  {
    const float* qb = qk + (size_t)b * 3072 + (G * 4) * DINO_ + 4 * m;
    #pragma unroll
    for (int j = 0; j < 4; ++j)
      #pragma unroll
      for (int t = 0; t < 3; ++t) {
        const float4 v = *(const float4*)(qb + j * DINO_ + 128 * t);
        qr[j][4*t] = v.x; qr[j][4*t+1] = v.y; qr[j][4*t+2] = v.z; qr[j][4*t+3] = v.w;
      }
  }
  float s[4][12];
  #pragma unroll
  for (int j = 0; j < 4; ++j)
    #pragma unroll
    for (int q = 0; q < 12; ++q) s[j][q] = 0.0f;
  float l = 0.0f;

  const float* gdino = dino + (size_t)b * N_ * DINO_;
  const float* gclamp = dino + ((size_t)B_ * N_ * DINO_ - 4); // last safe float4
  const int ntiles = (n1 - n0 + TROWS - 1) / TROWS;

  // stage tile 0 into buf0 (wave w stages segs w, w+4, ...)
  {
    const float* gb = gdino + (size_t)n0 * DINO_;
    for (int sg = w; sg < SEGS; sg += 4) {
      const float* g = gb + sg * 256 + 4 * lane;
      if (g > gclamp) g = gclamp;
      gld16(g, lds + sg * 256);
    }
  }
  __syncthreads();

  for (int t = 0; t < ntiles; ++t) {
    float* cur = lds + ((t & 1) ? TROWS * DINO_ : 0);
    float* nxt = lds + ((t & 1) ? 0 : TROWS * DINO_);
    if (t + 1 < ntiles) {
      const float* gb = gdino + (size_t)(n0 + (t + 1) * TROWS) * DINO_;
      for (int sg = w; sg < SEGS; sg += 4) {
        const float* g = gb + sg * 256 + 4 * lane;
        if (g > gclamp) g = gclamp;
        gld16(g, nxt + sg * 256);
      }
    }
    const int tb = n0 + t * TROWS;
    #pragma unroll 1
    for (int k = 0; k < 3; ++k) {
      const int slot = w + 4 * k;            // wave-uniform
      if (tb + slot >= n1) break;
      const float* xr = cur + slot * DINO_ + 4 * m;
      const float4 x0 = *(const float4*)(xr);
      const float4 x1 = *(const float4*)(xr + 128);
      const float4 x2 = *(const float4*)(xr + 256);
      const float xv[12] = {x0.x, x0.y, x0.z, x0.w,
                            x1.x, x1.y, x1.z, x1.w,
                            x2.x, x2.y, x2.z, x2.w};
      float va[4];
      #pragma unroll
      for (int j = 0; j < 4; ++j) {
        float a = 0.f, bacc = 0.f;
        #pragma unroll
        for (int q = 0; q < 12; q += 2) {
          a    += qr[j][q]     * xv[q];
          bacc += qr[j][q + 1] * xv[q + 1];
        }
        va[j] = a + bacc;
      }
      // fold 4 heads over 32 lanes
      float c0, c1;
      {
        const float t0 = __shfl_xor(va[0], 16), t1 = __shfl_xor(va[1], 16);
        const float t2 = __shfl_xor(va[2], 16), t3 = __shfl_xor(va[3], 16);
        c0 = b4 ? va[2] + t2 : va[0] + t0;
        c1 = b4 ? va[3] + t3 : va[1] + t1;
      }
      float d;
      {
        const float u0 = __shfl_xor(c0, 8), u1 = __shfl_xor(c1, 8);
        d = b3 ? c1 + u1 : c0 + u0;
      }
      d += __shfl_xor(d, 4);
      d += __shfl_xor(d, 2);
      d += __shfl_xor(d, 1);                 // octet holds its head's full logit
      const float p = __expf(d);
      l += p;                                // denominator of own head
      float P[4];
      P[0] = p;
      P[1] = __shfl_xor(p, 8);               // head hO^1
      P[2] = __shfl_xor(p, 16);              // head hO^2
      P[3] = __shfl_xor(P[1], 16);           // head hO^3
      #pragma unroll
      for (int j = 0; j < 4; ++j)
        #pragma unroll
        for (int q = 0; q < 12; ++q) s[j][q] += P[j] * xv[q];
    }
    __syncthreads();   // stage t+1 complete + cur free for overwrite at t+2
  }

  // ---- staged merge of 4 waves (aliased into the stage LDS; loop is done) ----
  float* sm0 = lds;                 // 64*SMP = 3328 floats
  float* sm1 = lds + 64 * SMP;      // total 6656 < 9216 available
  if (w >= 2) {
    float* dst = (w == 2 ? sm0 : sm1) + lane * SMP;
    #pragma unroll
    for (int j = 0; j < 4; ++j)
      #pragma unroll
      for (int t = 0; t < 3; ++t)
        *(float4*)(dst + j * 12 + 4 * t) =
            make_float4(s[j][4*t], s[j][4*t+1], s[j][4*t+2], s[j][4*t+3]);
    if ((lane & 7) == 0) lm[w - 2][4 * G + hO] = l;
  }
  __syncthreads();
  if (w < 2) {
    const float* src = (w == 0 ? sm0 : sm1) + lane * SMP;
    #pragma unroll
    for (int j = 0; j < 4; ++j)
      #pragma unroll
      for (int t = 0; t < 3; ++t) {
        const float4 v = *(const float4*)(src + j * 12 + 4 * t);
        s[j][4*t] += v.x; s[j][4*t+1] += v.y; s[j][4*t+2] += v.z; s[j][4*t+3] += v.w;
      }
    l += lm[w][4 * G + hO];
  }
  __syncthreads();
  if (w == 1) {
    float* dst = sm0 + lane * SMP;
    #pragma unroll
    for (int j = 0; j < 4; ++j)
      #pragma unroll
      for (int t = 0; t < 3; ++t)
        *(float4*)(dst + j * 12 + 4 * t) =
            make_float4(s[j][4*t], s[j][4*t+1], s[j][4*t+2], s[j][4*t+3]);
    if ((lane & 7) == 0) lm[0][4 * G + hO] = l;
  }
  __syncthreads();
  if (w == 0) {
    const float* src = sm0 + lane * SMP;
    #pragma unroll
    for (int j = 0; j < 4; ++j)
      #pragma unroll
      for (int t = 0; t < 3; ++t) {
        const float4 v = *(const float4*)(src + j * 12 + 4 * t);
        s[j][4*t] += v.x; s[j][4*t+1] += v.y; s[j][4*t+2] += v.z; s[j][4*t+3] += v.w;
      }
    l += lm[0][4 * G + hO];
    float* pso = ps + (size_t)blk * 3072;
    #pragma unroll
    for (int j = 0; j < 4; ++j) {
      const int h = 4 * G + (hO ^ j);
      float* o = pso + h * DINO_ + 4 * m;
      #pragma unroll
      for (int t = 0; t < 3; ++t)
        *(float4*)(o + 128 * t) =
            make_float4(s[j][4*t], s[j][4*t+1], s[j][4*t+2], s[j][4*t+3]);
    }
    if ((lane & 7) == 0) pl[blk * H_ + 4 * G + hO] = l;
  }
}

// ---------------------------------------------------------------------------
// kmf: fused chunk-merge + normalize + V-projection + LayerNorm.
// grid 128 x 512.
// ---------------------------------------------------------------------------
__global__ __launch_bounds__(512) void kmf(const float* __restrict__ ps,
                                           const float* __restrict__ pl,
                                           const float* __restrict__ Wv,
                                           const float* __restrict__ bv,
                                           const float* __restrict__ gamma,
                                           const float* __restrict__ beta,
                                           float* __restrict__ out) {
  const int b = blockIdx.x, tid = threadIdx.x;
  __shared__ float sfl[3072];
  __shared__ float rL[H_];
  float a[6];
  #pragma unroll
  for (int r = 0; r < 6; ++r) {
    const int e = tid + 512 * r;
    float acc = 0.0f;
    #pragma unroll
    for (int cc = 0; cc < CHUNKS; ++cc)
      acc += ps[(size_t)(b * CHUNKS + cc) * 3072 + e];
    a[r] = acc;
  }
  if (tid < H_) {
    float L = 0.0f;
    #pragma unroll
    for (int cc = 0; cc < CHUNKS; ++cc) L += pl[(b * CHUNKS + cc) * H_ + tid];
    rL[tid] = 1.0f / L;
  }
  __syncthreads();
  #pragma unroll
  for (int r = 0; r < 6; ++r) {
    const int e = tid + 512 * r;
    sfl[e] = a[r] * rL[e / DINO_];
  }
  __syncthreads();
  const int w = tid >> 6, lane = tid & 63;
  const float* srow = sfl + (tid >> 6) * DINO_;
  float acc = bv[tid];
  #pragma unroll 8
  for (int d = 0; d < DINO_; ++d) acc += srow[d] * Wv[d * CLIP_ + tid];
  // LayerNorm over 512
  float sum = wave_sum(acc);
  float sq  = wave_sum(acc * acc);
  __shared__ float rS[8], rQ[8];
  if (lane == 0) { rS[w] = sum; rQ[w] = sq; }
  __syncthreads();
  float tot = 0.0f, totq = 0.0f;
  #pragma unroll
  for (int i = 0; i < 8; ++i) { tot += rS[i]; totq += rQ[i]; }
  const float mu = tot * (1.0f / 512.0f);
  const float var = totq * (1.0f / 512.0f) - mu * mu;
  const float rstd = rsqrtf(var + 1e-5f);
  out[(size_t)b * CLIP_ + tid] = (acc - mu) * rstd * gamma[tid] + beta[tid];
}

// ---------------------------------------------------------------------------
extern "C" void kernel_launch(void* const* d_in, const int* in_sizes, int n_in,
                              void* d_out, int out_size, void* d_ws, size_t ws_size,
                              hipStream_t stream) {
  const float* dino  = (const float*)d_in[0];
  const float* clip  = (const float*)d_in[1];
  const float* Wq    = (const float*)d_in[2];
  const float* bq    = (const float*)d_in[3];
  const float* Wk    = (const float*)d_in[4];
  // d_in[5] = bk: softmax shift-invariant, dropped
  const float* Wv    = (const float*)d_in[6];
  const float* bv    = (const float*)d_in[7];
  const float* temp  = (const float*)d_in[8];
  const float* gamma = (const float*)d_in[9];
  const float* beta  = (const float*)d_in[10];
  float* out = (float*)d_out;

  float* ws  = (float*)d_ws;
  float* qkb = ws;                       // 128*3072            =   393,216 f
  float* ps  = qkb + 393216;             // 128*8*3072          = 3,145,728 f
  float* pl  = ps  + 3145728;            // 128*8*8             =     8,192 f
  // total ~14.2 MB

  kqq  <<<B_,           256, 0, stream>>>(clip, Wq, bq, Wk, temp, qkb);
  kmain<<<B_ * CHUNKS,  256, 0, stream>>>(dino, qkb, ps, pl);
  kmf  <<<B_,           512, 0, stream>>>(ps, pl, Wv, bv, gamma, beta, out);
}

// Round 4
// 470.616 us; speedup vs baseline: 1.0866x; 1.0866x over previous
//
#include <hip/hip_runtime.h>
#include <math.h>
#include <stdint.h>

#define B_    128
#define N_    1369
#define DINO_ 384
#define CLIP_ 512
#define H_    8
#define CHUNKS 6
#define CH     229   // ceil(1369/6); last chunk = 224
#define TROWS  8     // rows per tile (8*384*4B = 12 KiB per buffer)
#define DEPTH  4     // pipeline depth (buffers); 48 KiB total -> 3 blocks/CU
#define SEGW   3     // 1-KiB segments per wave per tile (wave-private)
#define SMP    52    // padded per-lane float stride in merge LDS

// ---------------------------------------------------------------------------
// helpers
// ---------------------------------------------------------------------------
__device__ __forceinline__ float wave_sum(float v) {
  v += __shfl_xor(v, 1);  v += __shfl_xor(v, 2);  v += __shfl_xor(v, 4);
  v += __shfl_xor(v, 8);  v += __shfl_xor(v, 16); v += __shfl_xor(v, 32);
  return v;
}

// async global->LDS copy, 16B per lane. LDS dest = base + lane*16 (HW rule).
__device__ __forceinline__ void gld16(const float* g, float* lds_base) {
  __builtin_amdgcn_global_load_lds(
      (const __attribute__((address_space(1))) void*)g,
      (__attribute__((address_space(3))) void*)lds_base, 16, 0, 0);
}

// ---------------------------------------------------------------------------
// kq: Q[b,c] = bq[c] + clip[b,:]·Wq[:,c].  grid (128,2) x 256.
// ---------------------------------------------------------------------------
__global__ __launch_bounds__(256) void kq(const float* __restrict__ clip,
                                          const float* __restrict__ Wq,
                                          const float* __restrict__ bq,
                                          float* __restrict__ Q) {
  const int b = blockIdx.x;
  const int c = blockIdx.y * 256 + threadIdx.x;
  __shared__ float cl[CLIP_];
  cl[threadIdx.x] = clip[b * CLIP_ + threadIdx.x];
  cl[threadIdx.x + 256] = clip[b * CLIP_ + threadIdx.x + 256];
  __syncthreads();
  float acc = bq[c];
  #pragma unroll 8
  for (int j = 0; j < CLIP_; ++j) acc += cl[j] * Wq[j * CLIP_ + c];
  Q[b * CLIP_ + c] = acc;
}

// ---------------------------------------------------------------------------
// kqk: qk[b, h*384+j] = rs * sum_d Wk[j][h*64+d] * Q[b, h*64+d].
// grid (128,12) x 256.
// ---------------------------------------------------------------------------
__global__ __launch_bounds__(256) void kqk(const float* __restrict__ Wk,
                                           const float* __restrict__ Q,
                                           const float* __restrict__ temp,
                                           float* __restrict__ qkout) {
  const int b = blockIdx.x;
  const int e = blockIdx.y * 256 + threadIdx.x;   // 0..3071
  __shared__ float qs[CLIP_];
  qs[threadIdx.x] = Q[b * CLIP_ + threadIdx.x];
  qs[threadIdx.x + 256] = Q[b * CLIP_ + threadIdx.x + 256];
  __syncthreads();
  const int h = e / DINO_;
  const int j = e - h * DINO_;
  const float rs = 1.0f / (8.0f * temp[0]);       // scale = sqrt(64)*temperature
  const float* wrow = Wk + (size_t)j * CLIP_ + h * 64;
  const float* qrow = qs + h * 64;
  float a0 = 0.f, a1 = 0.f, a2 = 0.f, a3 = 0.f;
  #pragma unroll
  for (int d = 0; d < 64; d += 4) {
    const float4 wv = *(const float4*)(wrow + d);
    const float4 qv = *(const float4*)(qrow + d);
    a0 += wv.x * qv.x;  a1 += wv.y * qv.y;
    a2 += wv.z * qv.z;  a3 += wv.w * qv.w;
  }
  qkout[(size_t)b * 3072 + e] = ((a0 + a1) + (a2 + a3)) * rs;
}

// ---------------------------------------------------------------------------
// kmain: fused logits + (no-max) softmax numerator + attn-weighted dino sum.
// grid 768 x 256 (exactly 3 blocks/CU at launch_bounds(256,3)).
//
// v4: wave-private 4-deep prefetch pipeline, NO barriers in the main loop.
// Wave w stages LDS segments 3w..3w+2 of each tile = exactly its own rows
// (2w, 2w+1), so no LDS data crosses waves.  Each wave keeps 9 gld16 (3
// tiles) outstanding and gates consumption with s_waitcnt vmcnt(6) (tail
// iterations always issue 3 clamped loads into the dead buffer so the
// vmcnt arithmetic stays constant).  Extra compiler vmem ops only
// over-drain (safe).
//
// g=4 lane layout (verified r3): 32-lane group G = lane>>5 serves heads
// 4G..4G+3; m = lane&31 owns dims 4m+128t+z -> 3 ds_read_b128 per row.
// Logit fold: 2 select-folds (xor16, xor8) + xor4/2/1, exp once,
// 3-shfl broadcast.  96 FMA/lane/row (optimal).
// ---------------------------------------------------------------------------
__global__ __launch_bounds__(256, 3) void kmain(const float* __restrict__ dino,
                                                const float* __restrict__ qk,
                                                float* __restrict__ ps,
                                                float* __restrict__ pl) {
  __shared__ float lds[DEPTH * TROWS * DINO_];   // 12288 floats = 48 KiB
  __shared__ float lm[2][H_];

  const int blk = blockIdx.x;
  const int b = blk / CHUNKS;
  const int c = blk - b * CHUNKS;
  const int n0 = c * CH;
  const int n1 = min(N_, n0 + CH);
  const int tid = threadIdx.x, w = tid >> 6, lane = tid & 63;
  const int m = lane & 31;
  const int G = lane >> 5;
  const int b4 = (lane >> 4) & 1, b3 = (lane >> 3) & 1;
  const int hO = 2 * b4 + b3;

  // qr[j][k]: q for relative head j (absolute 4G+j), dim 4m + 128t + z
  float qr[4][12];
  {
    const float* qb = qk + (size_t)b * 3072 + (G * 4) * DINO_ + 4 * m;
    #pragma unroll
    for (int j = 0; j < 4; ++j)
      #pragma unroll
      for (int t = 0; t < 3; ++t) {
        const float4 v = *(const float4*)(qb + j * DINO_ + 128 * t);
        qr[j][4*t] = v.x; qr[j][4*t+1] = v.y; qr[j][4*t+2] = v.z; qr[j][4*t+3] = v.w;
      }
  }
  // drain qr loads so the pipeline's vmcnt bookkeeping starts from 0
  asm volatile("s_waitcnt vmcnt(0)" ::: "memory");

  float s[4][12];
  #pragma unroll
  for (int j = 0; j < 4; ++j)
    #pragma unroll
    for (int q = 0; q < 12; ++q) s[j][q] = 0.0f;
  float l = 0.0f;

  const float* gdino = dino + (size_t)b * N_ * DINO_;
  const float* gclamp = dino + ((size_t)B_ * N_ * DINO_ - 4); // last safe float4
  const int ntiles = (n1 - n0 + TROWS - 1) / TROWS;           // >= 28

  // prologue: issue tiles 0..2 (wave-private segments only)
  #pragma unroll
  for (int pt = 0; pt < 3; ++pt) {
    const float* gb = gdino + (size_t)(n0 + pt * TROWS) * DINO_;
    float* buf = lds + pt * (TROWS * DINO_);
    #pragma unroll
    for (int j = 0; j < SEGW; ++j) {
      const int sg = SEGW * w + j;
      const float* g = gb + sg * 256 + 4 * lane;
      if (g > gclamp) g = gclamp;
      gld16(g, buf + sg * 256);
    }
  }

  for (int t = 0; t < ntiles; ++t) {
    // oldest tile (t) complete; tiles t+1, t+2 (6 ops) may remain in flight
    asm volatile("s_waitcnt vmcnt(6)" ::: "memory");
    __builtin_amdgcn_sched_barrier(0);
    // always issue tile t+3 (clamped at tail; lands in a dead buffer)
    {
      const float* gb = gdino + (size_t)(n0 + (t + 3) * TROWS) * DINO_;
      float* buf = lds + ((t + 3) & 3) * (TROWS * DINO_);
      #pragma unroll
      for (int j = 0; j < SEGW; ++j) {
        const int sg = SEGW * w + j;
        const float* g = gb + sg * 256 + 4 * lane;
        if (g > gclamp) g = gclamp;
        gld16(g, buf + sg * 256);
      }
    }
    const float* cur = lds + (t & 3) * (TROWS * DINO_);
    const int tb = n0 + t * TROWS;
    #pragma unroll
    for (int k = 0; k < 2; ++k) {
      const int slot = 2 * w + k;            // wave-uniform row in tile
      if (tb + slot < n1) {
        const float* xr = cur + slot * DINO_ + 4 * m;
        const float4 x0 = *(const float4*)(xr);
        const float4 x1 = *(const float4*)(xr + 128);
        const float4 x2 = *(const float4*)(xr + 256);
        const float xv[12] = {x0.x, x0.y, x0.z, x0.w,
                              x1.x, x1.y, x1.z, x1.w,
                              x2.x, x2.y, x2.z, x2.w};
        float va[4];
        #pragma unroll
        for (int j = 0; j < 4; ++j) {
          float a = 0.f, bacc = 0.f;
          #pragma unroll
          for (int q = 0; q < 12; q += 2) {
            a    += qr[j][q]     * xv[q];
            bacc += qr[j][q + 1] * xv[q + 1];
          }
          va[j] = a + bacc;
        }
        // fold 4 heads over 32 lanes
        float c0, c1;
        {
          const float t0 = __shfl_xor(va[0], 16), t1 = __shfl_xor(va[1], 16);
          const float t2 = __shfl_xor(va[2], 16), t3 = __shfl_xor(va[3], 16);
          c0 = b4 ? va[2] + t2 : va[0] + t0;
          c1 = b4 ? va[3] + t3 : va[1] + t1;
        }
        float d;
        {
          const float u0 = __shfl_xor(c0, 8), u1 = __shfl_xor(c1, 8);
          d = b3 ? c1 + u1 : c0 + u0;
        }
        d += __shfl_xor(d, 4);
        d += __shfl_xor(d, 2);
        d += __shfl_xor(d, 1);               // octet holds its head's full logit
        const float p = __expf(d);
        l += p;                              // denominator of own head
        float P[4];
        P[0] = p;
        P[1] = __shfl_xor(p, 8);             // head hO^1
        P[2] = __shfl_xor(p, 16);            // head hO^2
        P[3] = __shfl_xor(P[1], 16);         // head hO^3
        #pragma unroll
        for (int j = 0; j < 4; ++j)
          #pragma unroll
          for (int q = 0; q < 12; ++q) s[j][q] += P[j] * xv[q];
      }
    }
  }

  asm volatile("s_waitcnt vmcnt(0)" ::: "memory");
  __syncthreads();

  // ---- staged merge of 4 waves (aliased into the stage LDS; loop is done) ----
  float* sm0 = lds;                 // 64*SMP = 3328 floats
  float* sm1 = lds + 64 * SMP;      // total 6656 << 12288 available
  if (w >= 2) {
    float* dst = (w == 2 ? sm0 : sm1) + lane * SMP;
    #pragma unroll
    for (int j = 0; j < 4; ++j)
      #pragma unroll
      for (int t = 0; t < 3; ++t)
        *(float4*)(dst + j * 12 + 4 * t) =
            make_float4(s[j][4*t], s[j][4*t+1], s[j][4*t+2], s[j][4*t+3]);
    if ((lane & 7) == 0) lm[w - 2][4 * G + hO] = l;
  }
  __syncthreads();
  if (w < 2) {
    const float* src = (w == 0 ? sm0 : sm1) + lane * SMP;
    #pragma unroll
    for (int j = 0; j < 4; ++j)
      #pragma unroll
      for (int t = 0; t < 3; ++t) {
        const float4 v = *(const float4*)(src + j * 12 + 4 * t);
        s[j][4*t] += v.x; s[j][4*t+1] += v.y; s[j][4*t+2] += v.z; s[j][4*t+3] += v.w;
      }
    l += lm[w][4 * G + hO];
  }
  __syncthreads();
  if (w == 1) {
    float* dst = sm0 + lane * SMP;
    #pragma unroll
    for (int j = 0; j < 4; ++j)
      #pragma unroll
      for (int t = 0; t < 3; ++t)
        *(float4*)(dst + j * 12 + 4 * t) =
            make_float4(s[j][4*t], s[j][4*t+1], s[j][4*t+2], s[j][4*t+3]);
    if ((lane & 7) == 0) lm[0][4 * G + hO] = l;
  }
  __syncthreads();
  if (w == 0) {
    const float* src = sm0 + lane * SMP;
    #pragma unroll
    for (int j = 0; j < 4; ++j)
      #pragma unroll
      for (int t = 0; t < 3; ++t) {
        const float4 v = *(const float4*)(src + j * 12 + 4 * t);
        s[j][4*t] += v.x; s[j][4*t+1] += v.y; s[j][4*t+2] += v.z; s[j][4*t+3] += v.w;
      }
    l += lm[0][4 * G + hO];
    float* pso = ps + (size_t)blk * 3072;
    #pragma unroll
    for (int j = 0; j < 4; ++j) {
      const int h = 4 * G + (hO ^ j);
      float* o = pso + h * DINO_ + 4 * m;
      #pragma unroll
      for (int t = 0; t < 3; ++t)
        *(float4*)(o + 128 * t) =
            make_float4(s[j][4*t], s[j][4*t+1], s[j][4*t+2], s[j][4*t+3]);
    }
    if ((lane & 7) == 0) pl[blk * H_ + 4 * G + hO] = l;
  }
}

// ---------------------------------------------------------------------------
// kmf: fused chunk-merge + normalize + V-projection + LayerNorm.
// grid 128 x 512.
// ---------------------------------------------------------------------------
__global__ __launch_bounds__(512) void kmf(const float* __restrict__ ps,
                                           const float* __restrict__ pl,
                                           const float* __restrict__ Wv,
                                           const float* __restrict__ bv,
                                           const float* __restrict__ gamma,
                                           const float* __restrict__ beta,
                                           float* __restrict__ out) {
  const int b = blockIdx.x, tid = threadIdx.x;
  __shared__ float sfl[3072];
  __shared__ float rL[H_];
  float a[6];
  #pragma unroll
  for (int r = 0; r < 6; ++r) {
    const int e = tid + 512 * r;
    float acc = 0.0f;
    #pragma unroll
    for (int cc = 0; cc < CHUNKS; ++cc)
      acc += ps[(size_t)(b * CHUNKS + cc) * 3072 + e];
    a[r] = acc;
  }
  if (tid < H_) {
    float L = 0.0f;
    #pragma unroll
    for (int cc = 0; cc < CHUNKS; ++cc) L += pl[(b * CHUNKS + cc) * H_ + tid];
    rL[tid] = 1.0f / L;
  }
  __syncthreads();
  #pragma unroll
  for (int r = 0; r < 6; ++r) {
    const int e = tid + 512 * r;
    sfl[e] = a[r] * rL[e / DINO_];
  }
  __syncthreads();
  const int w = tid >> 6, lane = tid & 63;
  const float* srow = sfl + (tid >> 6) * DINO_;
  float acc = bv[tid];
  #pragma unroll 8
  for (int d = 0; d < DINO_; ++d) acc += srow[d] * Wv[d * CLIP_ + tid];
  // LayerNorm over 512
  float sum = wave_sum(acc);
  float sq  = wave_sum(acc * acc);
  __shared__ float rS[8], rQ[8];
  if (lane == 0) { rS[w] = sum; rQ[w] = sq; }
  __syncthreads();
  float tot = 0.0f, totq = 0.0f;
  #pragma unroll
  for (int i = 0; i < 8; ++i) { tot += rS[i]; totq += rQ[i]; }
  const float mu = tot * (1.0f / 512.0f);
  const float var = totq * (1.0f / 512.0f) - mu * mu;
  const float rstd = rsqrtf(var + 1e-5f);
  out[(size_t)b * CLIP_ + tid] = (acc - mu) * rstd * gamma[tid] + beta[tid];
}

// ---------------------------------------------------------------------------
extern "C" void kernel_launch(void* const* d_in, const int* in_sizes, int n_in,
                              void* d_out, int out_size, void* d_ws, size_t ws_size,
                              hipStream_t stream) {
  const float* dino  = (const float*)d_in[0];
  const float* clip  = (const float*)d_in[1];
  const float* Wq    = (const float*)d_in[2];
  const float* bq    = (const float*)d_in[3];
  const float* Wk    = (const float*)d_in[4];
  // d_in[5] = bk: softmax shift-invariant, dropped
  const float* Wv    = (const float*)d_in[6];
  const float* bv    = (const float*)d_in[7];
  const float* temp  = (const float*)d_in[8];
  const float* gamma = (const float*)d_in[9];
  const float* beta  = (const float*)d_in[10];
  float* out = (float*)d_out;

  float* ws  = (float*)d_ws;
  float* Q   = ws;                       // 128*512            =    65,536 f
  float* qkb = Q   + 65536;              // 128*3072           =   393,216 f
  float* ps  = qkb + 393216;             // 128*6*3072         = 2,359,296 f
  float* pl  = ps  + 2359296;            // 128*6*8            =     6,144 f
  // total ~11.3 MB

  kq   <<<dim3(B_, 2),  256, 0, stream>>>(clip, Wq, bq, Q);
  kqk  <<<dim3(B_, 12), 256, 0, stream>>>(Wk, Q, temp, qkb);
  kmain<<<B_ * CHUNKS,  256, 0, stream>>>(dino, qkb, ps, pl);
  kmf  <<<B_,           512, 0, stream>>>(ps, pl, Wv, bv, gamma, beta, out);
}

// Round 5
// 470.162 us; speedup vs baseline: 1.0877x; 1.0010x over previous
//
#include <hip/hip_runtime.h>
#include <math.h>
#include <stdint.h>

#define B_    128
#define N_    1369
#define DINO_ 384
#define CLIP_ 512
#define H_    8
#define CHUNKS 6
#define CH     229   // ceil(1369/6); last chunk = 224
#define TROWS  8     // rows per tile (8*384*4B = 12 KiB per buffer)
#define DEPTH  4     // pipeline depth (buffers); 48 KiB total -> 3 blocks/CU
#define SEGW   3     // 1-KiB segments per wave per tile (wave-private)
#define SMP    52    // padded per-lane float stride in merge LDS

// ---------------------------------------------------------------------------
// helpers
// ---------------------------------------------------------------------------
__device__ __forceinline__ float wave_sum(float v) {
  v += __shfl_xor(v, 1);  v += __shfl_xor(v, 2);  v += __shfl_xor(v, 4);
  v += __shfl_xor(v, 8);  v += __shfl_xor(v, 16); v += __shfl_xor(v, 32);
  return v;
}

// async global->LDS copy, 16B per lane. LDS dest = base + lane*16 (HW rule).
__device__ __forceinline__ void gld16(const float* g, float* lds_base) {
  __builtin_amdgcn_global_load_lds(
      (const __attribute__((address_space(1))) void*)g,
      (__attribute__((address_space(3))) void*)lds_base, 16, 0, 0);
}

// ---------------------------------------------------------------------------
// kq: Q[b,c] = bq[c] + clip[b,:]·Wq[:,c].  grid (128,2) x 256.
// ---------------------------------------------------------------------------
__global__ __launch_bounds__(256) void kq(const float* __restrict__ clip,
                                          const float* __restrict__ Wq,
                                          const float* __restrict__ bq,
                                          float* __restrict__ Q) {
  const int b = blockIdx.x;
  const int c = blockIdx.y * 256 + threadIdx.x;
  __shared__ float cl[CLIP_];
  cl[threadIdx.x] = clip[b * CLIP_ + threadIdx.x];
  cl[threadIdx.x + 256] = clip[b * CLIP_ + threadIdx.x + 256];
  __syncthreads();
  float acc = bq[c];
  #pragma unroll 8
  for (int j = 0; j < CLIP_; ++j) acc += cl[j] * Wq[j * CLIP_ + c];
  Q[b * CLIP_ + c] = acc;
}

// ---------------------------------------------------------------------------
// kqk: qk[b, h*384+j] = rs * sum_d Wk[j][h*64+d] * Q[b, h*64+d].
// grid (128,12) x 256.
// ---------------------------------------------------------------------------
__global__ __launch_bounds__(256) void kqk(const float* __restrict__ Wk,
                                           const float* __restrict__ Q,
                                           const float* __restrict__ temp,
                                           float* __restrict__ qkout) {
  const int b = blockIdx.x;
  const int e = blockIdx.y * 256 + threadIdx.x;   // 0..3071
  __shared__ float qs[CLIP_];
  qs[threadIdx.x] = Q[b * CLIP_ + threadIdx.x];
  qs[threadIdx.x + 256] = Q[b * CLIP_ + threadIdx.x + 256];
  __syncthreads();
  const int h = e / DINO_;
  const int j = e - h * DINO_;
  const float rs = 1.0f / (8.0f * temp[0]);       // scale = sqrt(64)*temperature
  const float* wrow = Wk + (size_t)j * CLIP_ + h * 64;
  const float* qrow = qs + h * 64;
  float a0 = 0.f, a1 = 0.f, a2 = 0.f, a3 = 0.f;
  #pragma unroll
  for (int d = 0; d < 64; d += 4) {
    const float4 wv = *(const float4*)(wrow + d);
    const float4 qv = *(const float4*)(qrow + d);
    a0 += wv.x * qv.x;  a1 += wv.y * qv.y;
    a2 += wv.z * qv.z;  a3 += wv.w * qv.w;
  }
  qkout[(size_t)b * 3072 + e] = ((a0 + a1) + (a2 + a3)) * rs;
}

// ---------------------------------------------------------------------------
// kmain: fused logits + (no-max) softmax numerator + attn-weighted dino sum.
// grid 768 x 256 (exactly 3 blocks/CU at launch_bounds(256,3)).
//
// v5 = v4's wave-private barrier-free prefetch pipeline, PLUS a one-row
// software pipeline of the softmax fold: the accumulate of row r uses
// (xvP, PP) saved from row r-1, and executes while row r's 9-hop shuffle
// chain (xor16..xor1 fold -> exp -> broadcast) is still in flight.  The
// chain result is consumed one row later, so its ~800cy latency hides
// under 96 independent FMAs.  Invalid tail rows contribute p=0 (select,
// NaN-safe; LDS always holds finite clamped data).
// ---------------------------------------------------------------------------
__global__ __launch_bounds__(256, 3) void kmain(const float* __restrict__ dino,
                                                const float* __restrict__ qk,
                                                float* __restrict__ ps,
                                                float* __restrict__ pl) {
  __shared__ float lds[DEPTH * TROWS * DINO_];   // 12288 floats = 48 KiB
  __shared__ float lm[2][H_];

  const int blk = blockIdx.x;
  const int b = blk / CHUNKS;
  const int c = blk - b * CHUNKS;
  const int n0 = c * CH;
  const int n1 = min(N_, n0 + CH);
  const int tid = threadIdx.x, w = tid >> 6, lane = tid & 63;
  const int m = lane & 31;
  const int G = lane >> 5;
  const int b4 = (lane >> 4) & 1, b3 = (lane >> 3) & 1;
  const int hO = 2 * b4 + b3;

  // qr[j][k]: q for relative head j (absolute 4G+j), dim 4m + 128t + z
  float qr[4][12];
  {
    const float* qb = qk + (size_t)b * 3072 + (G * 4) * DINO_ + 4 * m;
    #pragma unroll
    for (int j = 0; j < 4; ++j)
      #pragma unroll
      for (int t = 0; t < 3; ++t) {
        const float4 v = *(const float4*)(qb + j * DINO_ + 128 * t);
        qr[j][4*t] = v.x; qr[j][4*t+1] = v.y; qr[j][4*t+2] = v.z; qr[j][4*t+3] = v.w;
      }
  }
  // drain qr loads so the pipeline's vmcnt bookkeeping starts from 0
  asm volatile("s_waitcnt vmcnt(0)" ::: "memory");

  float s[4][12];
  #pragma unroll
  for (int j = 0; j < 4; ++j)
    #pragma unroll
    for (int q = 0; q < 12; ++q) s[j][q] = 0.0f;
  float l = 0.0f;

  // one-row software-pipeline state: prev row's x fragment + broadcast P
  float xvP[12], PP[4];
  #pragma unroll
  for (int q = 0; q < 12; ++q) xvP[q] = 0.0f;
  #pragma unroll
  for (int j = 0; j < 4; ++j) PP[j] = 0.0f;

  const float* gdino = dino + (size_t)b * N_ * DINO_;
  const float* gclamp = dino + ((size_t)B_ * N_ * DINO_ - 4); // last safe float4
  const int ntiles = (n1 - n0 + TROWS - 1) / TROWS;           // >= 28

  // prologue: issue tiles 0..2 (wave-private segments only)
  #pragma unroll
  for (int pt = 0; pt < 3; ++pt) {
    const float* gb = gdino + (size_t)(n0 + pt * TROWS) * DINO_;
    float* buf = lds + pt * (TROWS * DINO_);
    #pragma unroll
    for (int j = 0; j < SEGW; ++j) {
      const int sg = SEGW * w + j;
      const float* g = gb + sg * 256 + 4 * lane;
      if (g > gclamp) g = gclamp;
      gld16(g, buf + sg * 256);
    }
  }

  for (int t = 0; t < ntiles; ++t) {
    // oldest tile (t) complete; tiles t+1, t+2 (6 ops) may remain in flight
    asm volatile("s_waitcnt vmcnt(6)" ::: "memory");
    // always issue tile t+3 (clamped at tail; lands in the retired buffer)
    {
      const float* gb = gdino + (size_t)(n0 + (t + 3) * TROWS) * DINO_;
      float* buf = lds + ((t + 3) & 3) * (TROWS * DINO_);
      #pragma unroll
      for (int j = 0; j < SEGW; ++j) {
        const int sg = SEGW * w + j;
        const float* g = gb + sg * 256 + 4 * lane;
        if (g > gclamp) g = gclamp;
        gld16(g, buf + sg * 256);
      }
    }
    const float* cur = lds + (t & 3) * (TROWS * DINO_);
    const int tb = n0 + t * TROWS;
    #pragma unroll
    for (int k = 0; k < 2; ++k) {
      const int slot = 2 * w + k;              // wave-uniform row in tile
      const bool valid = (tb + slot) < n1;
      const float* xr = cur + slot * DINO_ + 4 * m;
      const float4 x0 = *(const float4*)(xr);
      const float4 x1 = *(const float4*)(xr + 128);
      const float4 x2 = *(const float4*)(xr + 256);
      const float xv[12] = {x0.x, x0.y, x0.z, x0.w,
                            x1.x, x1.y, x1.z, x1.w,
                            x2.x, x2.y, x2.z, x2.w};
      // current row's logit partials + fold chain (long latency, consumed
      // only after the prev-row accumulate below)
      float va[4];
      #pragma unroll
      for (int j = 0; j < 4; ++j) {
        float a = 0.f, bacc = 0.f;
        #pragma unroll
        for (int q = 0; q < 12; q += 2) {
          a    += qr[j][q]     * xv[q];
          bacc += qr[j][q + 1] * xv[q + 1];
        }
        va[j] = a + bacc;
      }
      float c0, c1;
      {
        const float t0 = __shfl_xor(va[0], 16), t1 = __shfl_xor(va[1], 16);
        const float t2 = __shfl_xor(va[2], 16), t3 = __shfl_xor(va[3], 16);
        c0 = b4 ? va[2] + t2 : va[0] + t0;
        c1 = b4 ? va[3] + t3 : va[1] + t1;
      }
      float d;
      {
        const float u0 = __shfl_xor(c0, 8), u1 = __shfl_xor(c1, 8);
        d = b3 ? c1 + u1 : c0 + u0;
      }
      d += __shfl_xor(d, 4);
      d += __shfl_xor(d, 2);
      d += __shfl_xor(d, 1);                   // octet holds its head's full logit

      // ---- accumulate PREVIOUS row (independent FMAs hide the chain) ----
      #pragma unroll
      for (int j = 0; j < 4; ++j)
        #pragma unroll
        for (int q = 0; q < 12; ++q) s[j][q] += PP[j] * xvP[q];

      // finish current row: exp + broadcast, save as prev
      const float p = valid ? __expf(d) : 0.0f;
      l += p;                                  // denominator of own head
      PP[0] = p;
      PP[1] = __shfl_xor(p, 8);                // head hO^1
      PP[2] = __shfl_xor(p, 16);               // head hO^2
      PP[3] = __shfl_xor(PP[1], 16);           // head hO^3
      #pragma unroll
      for (int q = 0; q < 12; ++q) xvP[q] = xv[q];
    }
  }
  // drain the pipeline: accumulate the final row
  #pragma unroll
  for (int j = 0; j < 4; ++j)
    #pragma unroll
    for (int q = 0; q < 12; ++q) s[j][q] += PP[j] * xvP[q];

  asm volatile("s_waitcnt vmcnt(0)" ::: "memory");
  __syncthreads();

  // ---- staged merge of 4 waves (aliased into the stage LDS; loop is done) ----
  float* sm0 = lds;                 // 64*SMP = 3328 floats
  float* sm1 = lds + 64 * SMP;      // total 6656 << 12288 available
  if (w >= 2) {
    float* dst = (w == 2 ? sm0 : sm1) + lane * SMP;
    #pragma unroll
    for (int j = 0; j < 4; ++j)
      #pragma unroll
      for (int t = 0; t < 3; ++t)
        *(float4*)(dst + j * 12 + 4 * t) =
            make_float4(s[j][4*t], s[j][4*t+1], s[j][4*t+2], s[j][4*t+3]);
    if ((lane & 7) == 0) lm[w - 2][4 * G + hO] = l;
  }
  __syncthreads();
  if (w < 2) {
    const float* src = (w == 0 ? sm0 : sm1) + lane * SMP;
    #pragma unroll
    for (int j = 0; j < 4; ++j)
      #pragma unroll
      for (int t = 0; t < 3; ++t) {
        const float4 v = *(const float4*)(src + j * 12 + 4 * t);
        s[j][4*t] += v.x; s[j][4*t+1] += v.y; s[j][4*t+2] += v.z; s[j][4*t+3] += v.w;
      }
    l += lm[w][4 * G + hO];
  }
  __syncthreads();
  if (w == 1) {
    float* dst = sm0 + lane * SMP;
    #pragma unroll
    for (int j = 0; j < 4; ++j)
      #pragma unroll
      for (int t = 0; t < 3; ++t)
        *(float4*)(dst + j * 12 + 4 * t) =
            make_float4(s[j][4*t], s[j][4*t+1], s[j][4*t+2], s[j][4*t+3]);
    if ((lane & 7) == 0) lm[0][4 * G + hO] = l;
  }
  __syncthreads();
  if (w == 0) {
    const float* src = sm0 + lane * SMP;
    #pragma unroll
    for (int j = 0; j < 4; ++j)
      #pragma unroll
      for (int t = 0; t < 3; ++t) {
        const float4 v = *(const float4*)(src + j * 12 + 4 * t);
        s[j][4*t] += v.x; s[j][4*t+1] += v.y; s[j][4*t+2] += v.z; s[j][4*t+3] += v.w;
      }
    l += lm[0][4 * G + hO];
    float* pso = ps + (size_t)blk * 3072;
    #pragma unroll
    for (int j = 0; j < 4; ++j) {
      const int h = 4 * G + (hO ^ j);
      float* o = pso + h * DINO_ + 4 * m;
      #pragma unroll
      for (int t = 0; t < 3; ++t)
        *(float4*)(o + 128 * t) =
            make_float4(s[j][4*t], s[j][4*t+1], s[j][4*t+2], s[j][4*t+3]);
    }
    if ((lane & 7) == 0) pl[blk * H_ + 4 * G + hO] = l;
  }
}

// ---------------------------------------------------------------------------
// kmf: fused chunk-merge + normalize + V-projection + LayerNorm.
// grid 128 x 512.
// ---------------------------------------------------------------------------
__global__ __launch_bounds__(512) void kmf(const float* __restrict__ ps,
                                           const float* __restrict__ pl,
                                           const float* __restrict__ Wv,
                                           const float* __restrict__ bv,
                                           const float* __restrict__ gamma,
                                           const float* __restrict__ beta,
                                           float* __restrict__ out) {
  const int b = blockIdx.x, tid = threadIdx.x;
  __shared__ float sfl[3072];
  __shared__ float rL[H_];
  float a[6];
  #pragma unroll
  for (int r = 0; r < 6; ++r) {
    const int e = tid + 512 * r;
    float acc = 0.0f;
    #pragma unroll
    for (int cc = 0; cc < CHUNKS; ++cc)
      acc += ps[(size_t)(b * CHUNKS + cc) * 3072 + e];
    a[r] = acc;
  }
  if (tid < H_) {
    float L = 0.0f;
    #pragma unroll
    for (int cc = 0; cc < CHUNKS; ++cc) L += pl[(b * CHUNKS + cc) * H_ + tid];
    rL[tid] = 1.0f / L;
  }
  __syncthreads();
  #pragma unroll
  for (int r = 0; r < 6; ++r) {
    const int e = tid + 512 * r;
    sfl[e] = a[r] * rL[e / DINO_];
  }
  __syncthreads();
  const int w = tid >> 6, lane = tid & 63;
  const float* srow = sfl + (tid >> 6) * DINO_;
  float acc = bv[tid];
  #pragma unroll 8
  for (int d = 0; d < DINO_; ++d) acc += srow[d] * Wv[d * CLIP_ + tid];
  // LayerNorm over 512
  float sum = wave_sum(acc);
  float sq  = wave_sum(acc * acc);
  __shared__ float rS[8], rQ[8];
  if (lane == 0) { rS[w] = sum; rQ[w] = sq; }
  __syncthreads();
  float tot = 0.0f, totq = 0.0f;
  #pragma unroll
  for (int i = 0; i < 8; ++i) { tot += rS[i]; totq += rQ[i]; }
  const float mu = tot * (1.0f / 512.0f);
  const float var = totq * (1.0f / 512.0f) - mu * mu;
  const float rstd = rsqrtf(var + 1e-5f);
  out[(size_t)b * CLIP_ + tid] = (acc - mu) * rstd * gamma[tid] + beta[tid];
}

// ---------------------------------------------------------------------------
extern "C" void kernel_launch(void* const* d_in, const int* in_sizes, int n_in,
                              void* d_out, int out_size, void* d_ws, size_t ws_size,
                              hipStream_t stream) {
  const float* dino  = (const float*)d_in[0];
  const float* clip  = (const float*)d_in[1];
  const float* Wq    = (const float*)d_in[2];
  const float* bq    = (const float*)d_in[3];
  const float* Wk    = (const float*)d_in[4];
  // d_in[5] = bk: softmax shift-invariant, dropped
  const float* Wv    = (const float*)d_in[6];
  const float* bv    = (const float*)d_in[7];
  const float* temp  = (const float*)d_in[8];
  const float* gamma = (const float*)d_in[9];
  const float* beta  = (const float*)d_in[10];
  float* out = (float*)d_out;

  float* ws  = (float*)d_ws;
  float* Q   = ws;                       // 128*512            =    65,536 f
  float* qkb = Q   + 65536;              // 128*3072           =   393,216 f
  float* ps  = qkb + 393216;             // 128*6*3072         = 2,359,296 f
  float* pl  = ps  + 2359296;            // 128*6*8            =     6,144 f
  // total ~11.3 MB

  kq   <<<dim3(B_, 2),  256, 0, stream>>>(clip, Wq, bq, Q);
  kqk  <<<dim3(B_, 12), 256, 0, stream>>>(Wk, Q, temp, qkb);
  kmain<<<B_ * CHUNKS,  256, 0, stream>>>(dino, qkb, ps, pl);
  kmf  <<<B_,           512, 0, stream>>>(ps, pl, Wv, bv, gamma, beta, out);
}

// Round 6
// 466.184 us; speedup vs baseline: 1.0970x; 1.0085x over previous
//
#include <hip/hip_runtime.h>
#include <math.h>
#include <stdint.h>

#define B_    128
#define N_    1369
#define DINO_ 384
#define CLIP_ 512
#define H_    8
#define CHUNKS 6
#define CH     229   // ceil(1369/6); last chunk = 224
#define TROWS  8     // rows per tile (8*384*4B = 12 KiB per buffer)
#define DEPTH  4     // pipeline depth (buffers); 48 KiB total -> 3 blocks/CU
#define SEGW   3     // 1-KiB segments per wave per tile (wave-private)
#define SMP    52    // padded per-lane float stride in merge LDS

// ---------------------------------------------------------------------------
// helpers
// ---------------------------------------------------------------------------
__device__ __forceinline__ float wave_sum(float v) {
  v += __shfl_xor(v, 1);  v += __shfl_xor(v, 2);  v += __shfl_xor(v, 4);
  v += __shfl_xor(v, 8);  v += __shfl_xor(v, 16); v += __shfl_xor(v, 32);
  return v;
}

// Full 16-lane-row sum via DPP row_ror rotations: pure VALU, no LDS pipe.
// After 4 rotate-adds every lane of the 16-lane row holds the row sum.
__device__ __forceinline__ float sum16_dpp(float v) {
  v += __int_as_float(__builtin_amdgcn_update_dpp(
      0, __float_as_int(v), 0x121, 0xf, 0xf, false));   // row_ror:1
  v += __int_as_float(__builtin_amdgcn_update_dpp(
      0, __float_as_int(v), 0x122, 0xf, 0xf, false));   // row_ror:2
  v += __int_as_float(__builtin_amdgcn_update_dpp(
      0, __float_as_int(v), 0x124, 0xf, 0xf, false));   // row_ror:4
  v += __int_as_float(__builtin_amdgcn_update_dpp(
      0, __float_as_int(v), 0x128, 0xf, 0xf, false));   // row_ror:8
  return v;
}

// async global->LDS copy, 16B per lane. LDS dest = base + lane*16 (HW rule).
__device__ __forceinline__ void gld16(const float* g, float* lds_base) {
  __builtin_amdgcn_global_load_lds(
      (const __attribute__((address_space(1))) void*)g,
      (__attribute__((address_space(3))) void*)lds_base, 16, 0, 0);
}

// ---------------------------------------------------------------------------
// kq: Q[b,c] = bq[c] + clip[b,:]·Wq[:,c].  grid (128,2) x 256.
// ---------------------------------------------------------------------------
__global__ __launch_bounds__(256) void kq(const float* __restrict__ clip,
                                          const float* __restrict__ Wq,
                                          const float* __restrict__ bq,
                                          float* __restrict__ Q) {
  const int b = blockIdx.x;
  const int c = blockIdx.y * 256 + threadIdx.x;
  __shared__ float cl[CLIP_];
  cl[threadIdx.x] = clip[b * CLIP_ + threadIdx.x];
  cl[threadIdx.x + 256] = clip[b * CLIP_ + threadIdx.x + 256];
  __syncthreads();
  float acc = bq[c];
  #pragma unroll 8
  for (int j = 0; j < CLIP_; ++j) acc += cl[j] * Wq[j * CLIP_ + c];
  Q[b * CLIP_ + c] = acc;
}

// ---------------------------------------------------------------------------
// kqk: qk[b, h*384+j] = rs * sum_d Wk[j][h*64+d] * Q[b, h*64+d].
// grid (128,12) x 256.
// ---------------------------------------------------------------------------
__global__ __launch_bounds__(256) void kqk(const float* __restrict__ Wk,
                                           const float* __restrict__ Q,
                                           const float* __restrict__ temp,
                                           float* __restrict__ qkout) {
  const int b = blockIdx.x;
  const int e = blockIdx.y * 256 + threadIdx.x;   // 0..3071
  __shared__ float qs[CLIP_];
  qs[threadIdx.x] = Q[b * CLIP_ + threadIdx.x];
  qs[threadIdx.x + 256] = Q[b * CLIP_ + threadIdx.x + 256];
  __syncthreads();
  const int h = e / DINO_;
  const int j = e - h * DINO_;
  const float rs = 1.0f / (8.0f * temp[0]);       // scale = sqrt(64)*temperature
  const float* wrow = Wk + (size_t)j * CLIP_ + h * 64;
  const float* qrow = qs + h * 64;
  float a0 = 0.f, a1 = 0.f, a2 = 0.f, a3 = 0.f;
  #pragma unroll
  for (int d = 0; d < 64; d += 4) {
    const float4 wv = *(const float4*)(wrow + d);
    const float4 qv = *(const float4*)(qrow + d);
    a0 += wv.x * qv.x;  a1 += wv.y * qv.y;
    a2 += wv.z * qv.z;  a3 += wv.w * qv.w;
  }
  qkout[(size_t)b * 3072 + e] = ((a0 + a1) + (a2 + a3)) * rs;
}

// ---------------------------------------------------------------------------
// kmain: fused logits + (no-max) softmax numerator + attn-weighted dino sum.
// grid 768 x 256 (exactly 3 blocks/CU at launch_bounds(256,3)).
//
// v6: same wave-private barrier-free gld16 prefetch pipeline as v4/v5, but
// the softmax reduction uses ZERO LDS-pipe cross-lane ops.  Lane = (r, m):
// 16-lane DPP row r = lane>>4 serves heads {r, r+4}; m = lane&15 owns dims
// 64t + 4m + z (t=0..5).  Per dino row: 6 ds_read_b128 (4-way same-address
// broadcast across rows, conflict-free), two 24-FMA dots, two 4-step DPP
// row_ror reductions (pure VALU), two exps, 48 accumulate FMAs.  No
// ds_swizzle, no broadcast shuffles, no lgkmcnt on the fold chain.
// ---------------------------------------------------------------------------
__global__ __launch_bounds__(256, 3) void kmain(const float* __restrict__ dino,
                                                const float* __restrict__ qk,
                                                float* __restrict__ ps,
                                                float* __restrict__ pl) {
  __shared__ float lds[DEPTH * TROWS * DINO_];   // 12288 floats = 48 KiB
  __shared__ float lm[2][H_];

  const int blk = blockIdx.x;
  const int b = blk / CHUNKS;
  const int c = blk - b * CHUNKS;
  const int n0 = c * CH;
  const int n1 = min(N_, n0 + CH);
  const int tid = threadIdx.x, w = tid >> 6, lane = tid & 63;
  const int r = lane >> 4;           // DPP row: heads r and r+4
  const int m = lane & 15;
  const int off = 4 * m;             // dim offset within each 64-dim strip

  // qr0/qr1: q fragments for heads r and r+4, dims 64t + 4m + z
  float qr0[24], qr1[24];
  {
    const float* qb = qk + (size_t)b * 3072 + off;
    #pragma unroll
    for (int t = 0; t < 6; ++t) {
      const float4 v0 = *(const float4*)(qb + r * DINO_ + 64 * t);
      const float4 v1 = *(const float4*)(qb + (r + 4) * DINO_ + 64 * t);
      qr0[4*t] = v0.x; qr0[4*t+1] = v0.y; qr0[4*t+2] = v0.z; qr0[4*t+3] = v0.w;
      qr1[4*t] = v1.x; qr1[4*t+1] = v1.y; qr1[4*t+2] = v1.z; qr1[4*t+3] = v1.w;
    }
  }
  // drain qr loads so the pipeline's vmcnt bookkeeping starts from 0
  asm volatile("s_waitcnt vmcnt(0)" ::: "memory");

  float s0[24], s1[24];
  #pragma unroll
  for (int q = 0; q < 24; ++q) { s0[q] = 0.0f; s1[q] = 0.0f; }
  float l0 = 0.0f, l1 = 0.0f;

  const float* gdino = dino + (size_t)b * N_ * DINO_;
  const float* gclamp = dino + ((size_t)B_ * N_ * DINO_ - 4); // last safe float4
  const int ntiles = (n1 - n0 + TROWS - 1) / TROWS;           // >= 28

  // prologue: issue tiles 0..2 (wave-private segments only)
  #pragma unroll
  for (int pt = 0; pt < 3; ++pt) {
    const float* gb = gdino + (size_t)(n0 + pt * TROWS) * DINO_;
    float* buf = lds + pt * (TROWS * DINO_);
    #pragma unroll
    for (int j = 0; j < SEGW; ++j) {
      const int sg = SEGW * w + j;
      const float* g = gb + sg * 256 + 4 * lane;
      if (g > gclamp) g = gclamp;
      gld16(g, buf + sg * 256);
    }
  }

  for (int t = 0; t < ntiles; ++t) {
    // oldest tile (t) complete; tiles t+1, t+2 (6 ops) may remain in flight
    asm volatile("s_waitcnt vmcnt(6)" ::: "memory");
    // always issue tile t+3 (clamped at tail; lands in the retired buffer)
    {
      const float* gb = gdino + (size_t)(n0 + (t + 3) * TROWS) * DINO_;
      float* buf = lds + ((t + 3) & 3) * (TROWS * DINO_);
      #pragma unroll
      for (int j = 0; j < SEGW; ++j) {
        const int sg = SEGW * w + j;
        const float* g = gb + sg * 256 + 4 * lane;
        if (g > gclamp) g = gclamp;
        gld16(g, buf + sg * 256);
      }
    }
    const float* cur = lds + (t & 3) * (TROWS * DINO_);
    const int tb = n0 + t * TROWS;
    #pragma unroll
    for (int k = 0; k < 2; ++k) {
      const int slot = 2 * w + k;              // wave-uniform row in tile
      const bool valid = (tb + slot) < n1;
      const float* xr = cur + slot * DINO_ + off;
      float xv[24];
      #pragma unroll
      for (int t6 = 0; t6 < 6; ++t6) {
        const float4 xx = *(const float4*)(xr + 64 * t6);
        xv[4*t6] = xx.x; xv[4*t6+1] = xx.y; xv[4*t6+2] = xx.z; xv[4*t6+3] = xx.w;
      }
      // two head-dots with 2-way ILP each
      float a0 = 0.f, a1 = 0.f, b0 = 0.f, b1 = 0.f;
      #pragma unroll
      for (int q = 0; q < 24; q += 2) {
        a0 += qr0[q]     * xv[q];
        a1 += qr0[q + 1] * xv[q + 1];
        b0 += qr1[q]     * xv[q];
        b1 += qr1[q + 1] * xv[q + 1];
      }
      float va0 = sum16_dpp(a0 + a1);          // pure-VALU 16-lane reduce
      float va1 = sum16_dpp(b0 + b1);
      const float p0 = valid ? __expf(va0) : 0.0f;
      const float p1 = valid ? __expf(va1) : 0.0f;
      l0 += p0;
      l1 += p1;
      #pragma unroll
      for (int q = 0; q < 24; ++q) {
        s0[q] += p0 * xv[q];
        s1[q] += p1 * xv[q];
      }
    }
  }

  asm volatile("s_waitcnt vmcnt(0)" ::: "memory");
  __syncthreads();

  // ---- staged merge of 4 waves (aliased into the stage LDS; loop is done) ----
  // per-lane payload: 12 float4 = [s0(24) | s1(24)] at stride SMP
  float* sm0 = lds;                 // 64*SMP = 3328 floats
  float* sm1 = lds + 64 * SMP;      // total 6656 << 12288 available
  if (w >= 2) {
    float* dst = (w == 2 ? sm0 : sm1) + lane * SMP;
    #pragma unroll
    for (int t = 0; t < 6; ++t) {
      *(float4*)(dst + 4 * t)      = make_float4(s0[4*t], s0[4*t+1], s0[4*t+2], s0[4*t+3]);
      *(float4*)(dst + 24 + 4 * t) = make_float4(s1[4*t], s1[4*t+1], s1[4*t+2], s1[4*t+3]);
    }
    if (m == 0) { lm[w - 2][r] = l0; lm[w - 2][r + 4] = l1; }
  }
  __syncthreads();
  if (w < 2) {
    const float* src = (w == 0 ? sm0 : sm1) + lane * SMP;
    #pragma unroll
    for (int t = 0; t < 6; ++t) {
      const float4 v0 = *(const float4*)(src + 4 * t);
      const float4 v1 = *(const float4*)(src + 24 + 4 * t);
      s0[4*t] += v0.x; s0[4*t+1] += v0.y; s0[4*t+2] += v0.z; s0[4*t+3] += v0.w;
      s1[4*t] += v1.x; s1[4*t+1] += v1.y; s1[4*t+2] += v1.z; s1[4*t+3] += v1.w;
    }
    l0 += lm[w][r];
    l1 += lm[w][r + 4];
  }
  __syncthreads();
  if (w == 1) {
    float* dst = sm0 + lane * SMP;
    #pragma unroll
    for (int t = 0; t < 6; ++t) {
      *(float4*)(dst + 4 * t)      = make_float4(s0[4*t], s0[4*t+1], s0[4*t+2], s0[4*t+3]);
      *(float4*)(dst + 24 + 4 * t) = make_float4(s1[4*t], s1[4*t+1], s1[4*t+2], s1[4*t+3]);
    }
    if (m == 0) { lm[0][r] = l0; lm[0][r + 4] = l1; }
  }
  __syncthreads();
  if (w == 0) {
    const float* src = sm0 + lane * SMP;
    #pragma unroll
    for (int t = 0; t < 6; ++t) {
      const float4 v0 = *(const float4*)(src + 4 * t);
      const float4 v1 = *(const float4*)(src + 24 + 4 * t);
      s0[4*t] += v0.x; s0[4*t+1] += v0.y; s0[4*t+2] += v0.z; s0[4*t+3] += v0.w;
      s1[4*t] += v1.x; s1[4*t+1] += v1.y; s1[4*t+2] += v1.z; s1[4*t+3] += v1.w;
    }
    l0 += lm[0][r];
    l1 += lm[0][r + 4];
    float* pso = ps + (size_t)blk * 3072;
    #pragma unroll
    for (int t = 0; t < 6; ++t) {
      *(float4*)(pso + r * DINO_ + 64 * t + off) =
          make_float4(s0[4*t], s0[4*t+1], s0[4*t+2], s0[4*t+3]);
      *(float4*)(pso + (r + 4) * DINO_ + 64 * t + off) =
          make_float4(s1[4*t], s1[4*t+1], s1[4*t+2], s1[4*t+3]);
    }
    if (m == 0) { pl[blk * H_ + r] = l0; pl[blk * H_ + r + 4] = l1; }
  }
}

// ---------------------------------------------------------------------------
// kmf: fused chunk-merge + normalize + V-projection + LayerNorm.
// grid 128 x 512.
// ---------------------------------------------------------------------------
__global__ __launch_bounds__(512) void kmf(const float* __restrict__ ps,
                                           const float* __restrict__ pl,
                                           const float* __restrict__ Wv,
                                           const float* __restrict__ bv,
                                           const float* __restrict__ gamma,
                                           const float* __restrict__ beta,
                                           float* __restrict__ out) {
  const int b = blockIdx.x, tid = threadIdx.x;
  __shared__ float sfl[3072];
  __shared__ float rL[H_];
  float a[6];
  #pragma unroll
  for (int r = 0; r < 6; ++r) {
    const int e = tid + 512 * r;
    float acc = 0.0f;
    #pragma unroll
    for (int cc = 0; cc < CHUNKS; ++cc)
      acc += ps[(size_t)(b * CHUNKS + cc) * 3072 + e];
    a[r] = acc;
  }
  if (tid < H_) {
    float L = 0.0f;
    #pragma unroll
    for (int cc = 0; cc < CHUNKS; ++cc) L += pl[(b * CHUNKS + cc) * H_ + tid];
    rL[tid] = 1.0f / L;
  }
  __syncthreads();
  #pragma unroll
  for (int r = 0; r < 6; ++r) {
    const int e = tid + 512 * r;
    sfl[e] = a[r] * rL[e / DINO_];
  }
  __syncthreads();
  const int w = tid >> 6, lane = tid & 63;
  const float* srow = sfl + (tid >> 6) * DINO_;
  float acc = bv[tid];
  #pragma unroll 8
  for (int d = 0; d < DINO_; ++d) acc += srow[d] * Wv[d * CLIP_ + tid];
  // LayerNorm over 512
  float sum = wave_sum(acc);
  float sq  = wave_sum(acc * acc);
  __shared__ float rS[8], rQ[8];
  if (lane == 0) { rS[w] = sum; rQ[w] = sq; }
  __syncthreads();
  float tot = 0.0f, totq = 0.0f;
  #pragma unroll
  for (int i = 0; i < 8; ++i) { tot += rS[i]; totq += rQ[i]; }
  const float mu = tot * (1.0f / 512.0f);
  const float var = totq * (1.0f / 512.0f) - mu * mu;
  const float rstd = rsqrtf(var + 1e-5f);
  out[(size_t)b * CLIP_ + tid] = (acc - mu) * rstd * gamma[tid] + beta[tid];
}

// ---------------------------------------------------------------------------
extern "C" void kernel_launch(void* const* d_in, const int* in_sizes, int n_in,
                              void* d_out, int out_size, void* d_ws, size_t ws_size,
                              hipStream_t stream) {
  const float* dino  = (const float*)d_in[0];
  const float* clip  = (const float*)d_in[1];
  const float* Wq    = (const float*)d_in[2];
  const float* bq    = (const float*)d_in[3];
  const float* Wk    = (const float*)d_in[4];
  // d_in[5] = bk: softmax shift-invariant, dropped
  const float* Wv    = (const float*)d_in[6];
  const float* bv    = (const float*)d_in[7];
  const float* temp  = (const float*)d_in[8];
  const float* gamma = (const float*)d_in[9];
  const float* beta  = (const float*)d_in[10];
  float* out = (float*)d_out;

  float* ws  = (float*)d_ws;
  float* Q   = ws;                       // 128*512            =    65,536 f
  float* qkb = Q   + 65536;              // 128*3072           =   393,216 f
  float* ps  = qkb + 393216;             // 128*6*3072         = 2,359,296 f
  float* pl  = ps  + 2359296;            // 128*6*8            =     6,144 f
  // total ~11.3 MB

  kq   <<<dim3(B_, 2),  256, 0, stream>>>(clip, Wq, bq, Q);
  kqk  <<<dim3(B_, 12), 256, 0, stream>>>(Wk, Q, temp, qkb);
  kmain<<<B_ * CHUNKS,  256, 0, stream>>>(dino, qkb, ps, pl);
  kmf  <<<B_,           512, 0, stream>>>(ps, pl, Wv, bv, gamma, beta, out);
}